// Round 13
// baseline (258.509 us; speedup 1.0000x reference)
//
#include <hip/hip_runtime.h>
#include <hip/hip_bf16.h>

// ---------------------------------------------------------------------------
// R13: R12 + __launch_bounds__(256,6) on the encoder. Grid = 1056 blocks =
// 4.125/CU; with min-waves=4 the 32 CUs holding a 5th block ran it SERIALLY
// (enc tail). At VGPR 56 / LDS 17KB, 6 blocks/CU co-reside trivially -> tail
// absorbed. Branchless x-prefetch (clamped index). Everything else = R12
// (best known: enc 94.4us, no spill). Decoder: R1 fp32 (validated).
// Fixed harness overhead ~130us/iter (restore+poison dispatches) — immovable.
// ---------------------------------------------------------------------------

typedef __attribute__((ext_vector_type(8))) short bf16x8;
typedef __attribute__((ext_vector_type(4))) float f32x4;
typedef unsigned int uint;
typedef unsigned short ushort_t;

#define LOG2E  1.4426950408889634f
#define LOG2E2 2.8853900817779268f

__device__ __forceinline__ float rcp_fast(float x) { return __builtin_amdgcn_rcpf(x); }
__device__ __forceinline__ float exp2_fast(float x) { return __builtin_amdgcn_exp2f(x); }
__device__ __forceinline__ float sigf(float x) { return rcp_fast(1.0f + __expf(-x)); }
__device__ __forceinline__ float tanh_fast(float x) {
    x = fminf(fmaxf(x, -15.0f), 15.0f);
    float e = __expf(2.0f * x);
    return (e - 1.0f) * rcp_fast(e + 1.0f);
}
__device__ __forceinline__ ushort_t bf_hi(float f) {
    union { float f; uint u; } v; v.f = f;
    return (ushort_t)(v.u >> 16);
}
__device__ __forceinline__ ushort_t bf_rtn(float f) {
    union { float f; uint u; } v; v.f = f;
    return (ushort_t)((v.u + 0x7FFFu + ((v.u >> 16) & 1u)) >> 16);
}
__device__ __forceinline__ float bf_f(ushort_t h) {
    union { float f; uint u; } v; v.u = ((uint)h) << 16;
    return v.f;
}

// Pre-scaled (log2e; g by 2log2e) cell update, 5 exp2 + 2 rcp (exact algebra):
//   A=1+e^-f, B=1+e^-i, C=1+e^{2g};  c' = [c*B*C + (C-2)*A] * rcp(A*B*C)
__device__ __forceinline__ float cell_update_p(float xi, float xf, float xg,
                                               float xo, float& c) {
    float pi = exp2_fast(-xi);
    float pf = exp2_fast(-xf);
    float po = exp2_fast(-xo);
    float pg = exp2_fast(fminf(xg, 120.0f));
    float A = 1.0f + pf;
    float B = 1.0f + pi;
    float C = 1.0f + pg;
    float BC = B * C;
    float R  = rcp_fast(A * BC);
    float num = __builtin_fmaf(c, BC, (C - 2.0f) * A);
    float cc = num * R;
    c = cc;
    float e2 = exp2_fast(fminf(cc * LOG2E2, 120.0f));
    return (e2 - 1.0f) * rcp_fast((1.0f + po) * (e2 + 1.0f));
}

// ======================= encoder: H=64, T=50 ==============================
// 16 seqs/block; 4 waves; wave wv owns units 16wv..16wv+15 for all 4 gates.
// hb row: 32 dwords = 64 bf16 h (RTN), pad to 36 dwords.
#define HS 36

__global__ __launch_bounds__(256, 6) void enc13_kernel(
    const float* __restrict__ ax, const float* __restrict__ nx,
    const float* __restrict__ a_wih, const float* __restrict__ a_whh,
    const float* __restrict__ a_bih, const float* __restrict__ a_bhh,
    const float* __restrict__ n_wih, const float* __restrict__ n_whh,
    const float* __restrict__ n_bih, const float* __restrict__ n_bhh,
    float* __restrict__ nh_out, float* __restrict__ ah_out)
{
    const int tid = threadIdx.x, blk = blockIdx.x;
    const bool agent = (blk >= 1024);
    const int seq0 = (agent ? (blk - 1024) : blk) * 16;
    const float* __restrict__ x   = agent ? ax : nx;
    const float* __restrict__ wih = agent ? a_wih : n_wih;
    const float* __restrict__ whh = agent ? a_whh : n_whh;
    const float* __restrict__ bih = agent ? a_bih : n_bih;
    const float* __restrict__ bhh = agent ? a_bhh : n_bhh;
    float* __restrict__ hout = agent ? ah_out : nh_out;

    const int lane = tid & 63, wv = tid >> 6;
    const int col = lane & 15, quad = lane >> 4;

    __shared__ __attribute__((aligned(16))) uint hb[2][16][HS];
    __shared__ __attribute__((aligned(16))) ushort_t xb[50][16][8];

    // A fragments: Whh rows, single RTN bf16, pre-scaled by log2e (2log2e for
    // the g gate). A row = g*64+16wv+col.
    bf16x8 Aw[4][2];
    #pragma unroll
    for (int g = 0; g < 4; ++g) {
        const float sc = (g == 2) ? LOG2E2 : LOG2E;
        #pragma unroll
        for (int kt = 0; kt < 2; ++kt) {
            const float* p = whh + (size_t)(g * 64 + 16 * wv + col) * 64 + kt * 32 + quad * 8;
            float4 v0 = *(const float4*)p;
            float4 v1 = *(const float4*)(p + 4);
            float vv[8] = { v0.x, v0.y, v0.z, v0.w, v1.x, v1.y, v1.z, v1.w };
            bf16x8 h8;
            #pragma unroll
            for (int j = 0; j < 8; ++j) h8[j] = (short)bf_rtn(vv[j] * sc);
            Aw[g][kt] = h8;
        }
    }

    // 3rd-tile A fragments (x + bias, pre-scaled): nonzero only on quad 0.
    bf16x8 Ax[4];
    #pragma unroll
    for (int g = 0; g < 4; ++g) {
        const float sc = (g == 2) ? LOG2E2 : LOG2E;
        bf16x8 a;
        #pragma unroll
        for (int j = 0; j < 8; ++j) a[j] = 0;
        if (quad == 0) {
            const int row = g * 64 + 16 * wv + col;
            float w0 = wih[2 * row] * sc, w1 = wih[2 * row + 1] * sc;
            float b  = (bih[row] + bhh[row]) * sc;
            ushort_t w0h = bf_hi(w0), w1h = bf_hi(w1);
            ushort_t bh  = bf_hi(b);
            a[0] = (short)w0h;
            a[1] = (short)w1h;
            a[2] = (short)bf_hi(w0 - bf_f(w0h));
            a[3] = (short)bf_hi(w1 - bf_f(w1h));
            a[4] = (short)w0h;
            a[5] = (short)w1h;
            a[6] = (short)bh;
            a[7] = (short)bf_hi(b - bf_f(bh));
        }
        Ax[g] = a;
    }

    for (int idx = tid; idx < 50 * 16; idx += 256) {
        const int t = idx >> 4, s = idx & 15;
        const float* xp = x + (size_t)(seq0 + s) * 100 + 2 * t;
        float x0 = xp[0], x1 = xp[1];
        ushort_t h0 = bf_hi(x0), h1 = bf_hi(x1);
        ushort_t* e = &xb[t][s][0];
        e[0] = h0; e[1] = h1;
        e[2] = h0; e[3] = h1;
        e[4] = bf_hi(x0 - bf_f(h0));
        e[5] = bf_hi(x1 - bf_f(h1));
        e[6] = 0x3F80; e[7] = 0x3F80;
    }
    for (int i = tid; i < 16 * HS; i += 256) (&hb[0][0][0])[i] = 0u;
    __syncthreads();

    float c[4] = {0.f, 0.f, 0.f, 0.f};
    float hv[4];
    bf16x8 Bx = *(const bf16x8*)&xb[0][col][0];   // prefetched x-tile, t=0

    for (int t = 0; t < 50; ++t) {
        const int cur = t & 1, nxt = cur ^ 1;

        const f32x4 z4 = {0.f, 0.f, 0.f, 0.f};
        f32x4 acc[4];
        #pragma unroll
        for (int g = 0; g < 4; ++g)
            acc[g] = __builtin_amdgcn_mfma_f32_16x16x32_bf16(Ax[g], Bx, z4, 0, 0, 0);

        // Whh @ h: 1 MFMA per gate per kt
        #pragma unroll
        for (int kt = 0; kt < 2; ++kt) {
            bf16x8 Bhi = *(const bf16x8*)&hb[cur][col][kt * 16 + quad * 4];
            #pragma unroll
            for (int g = 0; g < 4; ++g)
                acc[g] = __builtin_amdgcn_mfma_f32_16x16x32_bf16(Aw[g][kt], Bhi, acc[g], 0, 0, 0);
        }

        // cell update: lane owns seq=col, units 16wv + 4quad + r
        #pragma unroll
        for (int r = 0; r < 4; ++r)
            hv[r] = cell_update_p(acc[0][r], acc[1][r], acc[2][r], acc[3][r], c[r]);

        // pack h (packed RTN cvt) -> LDS
        {
            __hip_bfloat162 p01 = __float22bfloat162_rn(make_float2(hv[0], hv[1]));
            __hip_bfloat162 p23 = __float22bfloat162_rn(make_float2(hv[2], hv[3]));
            uint2 hi2;
            union { __hip_bfloat162 b; uint u; } c0, c1;
            c0.b = p01; c1.b = p23;
            hi2.x = c0.u;
            hi2.y = c1.u;
            const int di = 8 * wv + 2 * quad;
            *(uint2*)&hb[nxt][col][di] = hi2;
        }
        // branchless prefetch of next x-tile (xb read-only; index clamped)
        {
            const int tn = (t < 49) ? (t + 1) : 49;
            Bx = *(const bf16x8*)&xb[tn][col][0];
        }
        __syncthreads();
    }

    // peeled final store (hv holds t=49 values)
    {
        float4 o4 = make_float4(hv[0], hv[1], hv[2], hv[3]);
        *(float4*)(hout + (size_t)(seq0 + col) * 64 + 16 * wv + 4 * quad) = o4;
    }
}

// ============== decoder: R1-vintage fp32 (validated, ~25us) ================
__global__ __launch_bounds__(512) void dec13_kernel(
    const float* __restrict__ ah, const float* __restrict__ nh,
    const float* __restrict__ d_wih, const float* __restrict__ d_whh,
    const float* __restrict__ d_bih, const float* __restrict__ d_bhh,
    const float* __restrict__ e_w, const float* __restrict__ e_b,
    float* __restrict__ out)
{
    const int tid = threadIdx.x;
    const int blk = blockIdx.x;

    const int u  = tid >> 2;
    const int tt = tid & 3;
    const int r  = tt * 128 + u;

    float w[128];
    #pragma unroll
    for (int k = 0; k < 128; k += 4) {
        float4 aa = *(const float4*)(d_wih + r * 128 + k);
        float4 bb = *(const float4*)(d_whh + r * 128 + k);
        w[k]   = aa.x + bb.x;
        w[k+1] = aa.y + bb.y;
        w[k+2] = aa.z + bb.z;
        w[k+3] = aa.w + bb.w;
    }
    const float bias = d_bih[r] + d_bhh[r];

    __shared__ float hs[2][128];
    __shared__ float cs[2][128];
    __shared__ float gs[2][512];
    __shared__ float ews[2][128];
    __shared__ float ebs[2];

    if (tid < 256) {
        const int s = tid >> 7, j = tid & 127;
        const int gseq = blk * 2 + s;
        float v;
        if (j < 64) {
            v = ah[(size_t)gseq * 64 + j];
        } else {
            float acc = 0.0f;
            for (int n = 0; n < 32; ++n)
                acc += nh[(size_t)(gseq * 32 + n) * 64 + (j - 64)];
            v = acc * (1.0f / 32.0f);
        }
        hs[s][j] = v;
        cs[s][j] = 0.0f;
        ews[s][j] = e_w[tid];
    }
    if (tid < 2) ebs[tid] = e_b[tid];
    __syncthreads();

    for (int t = 0; t < 30; ++t) {
        #pragma unroll
        for (int s = 0; s < 2; ++s) {
            const float4* hp = (const float4*)(&hs[s][0]);
            float a0 = 0.f, a1 = 0.f, a2 = 0.f, a3 = 0.f;
            #pragma unroll
            for (int k = 0; k < 32; ++k) {
                float4 h4 = hp[k];
                a0 = __builtin_fmaf(w[4*k+0], h4.x, a0);
                a1 = __builtin_fmaf(w[4*k+1], h4.y, a1);
                a2 = __builtin_fmaf(w[4*k+2], h4.z, a2);
                a3 = __builtin_fmaf(w[4*k+3], h4.w, a3);
            }
            gs[s][tid] = bias + ((a0 + a1) + (a2 + a3));
        }
        __syncthreads();
        if (tid < 256) {
            const int s = tid >> 7, j = tid & 127;
            float4 g4 = *(const float4*)(&gs[s][4 * j]);
            float ig = sigf(g4.x), fg = sigf(g4.y);
            float gg = tanh_fast(g4.z), og = sigf(g4.w);
            float cc = fg * cs[s][j] + ig * gg;
            cs[s][j] = cc;
            hs[s][j] = og * tanh_fast(cc);
        }
        __syncthreads();
        {
            const int wv = tid >> 6, l = tid & 63;
            if (wv < 4) {
                const int s = wv >> 1, o = wv & 1;
                float p = hs[s][l] * ews[o][l] + hs[s][64 + l] * ews[o][64 + l];
                #pragma unroll
                for (int off = 32; off > 0; off >>= 1) p += __shfl_down(p, off);
                if (l == 0) out[((size_t)(blk * 2 + s) * 30 + t) * 2 + o] = p + ebs[o];
            }
        }
    }
}

extern "C" void kernel_launch(void* const* d_in, const int* in_sizes, int n_in,
                              void* d_out, int out_size, void* d_ws, size_t ws_size,
                              hipStream_t stream)
{
    const float* agent_traj = (const float*)d_in[0];
    const float* neigh_traj = (const float*)d_in[1];
    const float* a_wih = (const float*)d_in[2];
    const float* a_whh = (const float*)d_in[3];
    const float* a_bih = (const float*)d_in[4];
    const float* a_bhh = (const float*)d_in[5];
    const float* n_wih = (const float*)d_in[6];
    const float* n_whh = (const float*)d_in[7];
    const float* n_bih = (const float*)d_in[8];
    const float* n_bhh = (const float*)d_in[9];
    const float* d_wih = (const float*)d_in[10];
    const float* d_whh = (const float*)d_in[11];
    const float* d_bih = (const float*)d_in[12];
    const float* d_bhh = (const float*)d_in[13];
    const float* e_w   = (const float*)d_in[14];
    const float* e_b   = (const float*)d_in[15];
    float* out = (float*)d_out;

    float* nh_ws = (float*)d_ws;            // 16384*64 fp32
    float* ah_ws = nh_ws + 16384 * 64;      // 512*64 fp32

    enc13_kernel<<<dim3(1024 + 32), dim3(256), 0, stream>>>(
        agent_traj, neigh_traj,
        a_wih, a_whh, a_bih, a_bhh,
        n_wih, n_whh, n_bih, n_bhh,
        nh_ws, ah_ws);

    dec13_kernel<<<dim3(256), dim3(512), 0, stream>>>(
        ah_ws, nh_ws, d_wih, d_whh, d_bih, d_bhh, e_w, e_b, out);
}

// Round 14
// 246.130 us; speedup vs baseline: 1.0503x; 1.0503x over previous
//
#include <hip/hip_runtime.h>
#include <hip/hip_bf16.h>

// ---------------------------------------------------------------------------
// R14 = R12 verbatim (measured optimum: 246.9us total; enc 94.4us, VGPR 56,
// no spill). R13's (256,6) bound re-spilled (40 VGPR, +34MB scratch) — any
// launch-bounds cap below ~128 effective VGPRs on this loop trades spill for
// occupancy at a net loss (3rd confirmation: R4, R8, R13).
// Plateau evidence: trans count at algebraic min (5exp2+2rcp, further cut
// neutral), MFMA count min (12/step), TLP capped by problem at 4 waves/SIMD
// (R11's 1-wave variant -84us), ~130us/iter is fixed harness overhead.
// ---------------------------------------------------------------------------

typedef __attribute__((ext_vector_type(8))) short bf16x8;
typedef __attribute__((ext_vector_type(4))) float f32x4;
typedef unsigned int uint;
typedef unsigned short ushort_t;

#define LOG2E  1.4426950408889634f
#define LOG2E2 2.8853900817779268f

__device__ __forceinline__ float rcp_fast(float x) { return __builtin_amdgcn_rcpf(x); }
__device__ __forceinline__ float exp2_fast(float x) { return __builtin_amdgcn_exp2f(x); }
__device__ __forceinline__ float sigf(float x) { return rcp_fast(1.0f + __expf(-x)); }
__device__ __forceinline__ float tanh_fast(float x) {
    x = fminf(fmaxf(x, -15.0f), 15.0f);
    float e = __expf(2.0f * x);
    return (e - 1.0f) * rcp_fast(e + 1.0f);
}
__device__ __forceinline__ ushort_t bf_hi(float f) {
    union { float f; uint u; } v; v.f = f;
    return (ushort_t)(v.u >> 16);
}
__device__ __forceinline__ ushort_t bf_rtn(float f) {
    union { float f; uint u; } v; v.f = f;
    return (ushort_t)((v.u + 0x7FFFu + ((v.u >> 16) & 1u)) >> 16);
}
__device__ __forceinline__ float bf_f(ushort_t h) {
    union { float f; uint u; } v; v.u = ((uint)h) << 16;
    return v.f;
}

// Pre-scaled (log2e; g by 2log2e) cell update, 5 exp2 + 2 rcp:
//   A=1+e^-f, B=1+e^-i, C=1+e^{2g};  c' = [c*B*C + (C-2)*A] * rcp(A*B*C)
__device__ __forceinline__ float cell_update_p(float xi, float xf, float xg,
                                               float xo, float& c) {
    float pi = exp2_fast(-xi);
    float pf = exp2_fast(-xf);
    float po = exp2_fast(-xo);
    float pg = exp2_fast(fminf(xg, 120.0f));
    float A = 1.0f + pf;
    float B = 1.0f + pi;
    float C = 1.0f + pg;
    float BC = B * C;
    float R  = rcp_fast(A * BC);
    float num = __builtin_fmaf(c, BC, (C - 2.0f) * A);
    float cc = num * R;
    c = cc;
    float e2 = exp2_fast(fminf(cc * LOG2E2, 120.0f));
    return (e2 - 1.0f) * rcp_fast((1.0f + po) * (e2 + 1.0f));
}

// ======================= encoder: H=64, T=50 ==============================
// 16 seqs/block; 4 waves; wave wv owns units 16wv..16wv+15 for all 4 gates.
// hb row: 32 dwords = 64 bf16 h (RTN), pad to 36 dwords.
#define HS 36

__global__ __launch_bounds__(256, 4) void enc14_kernel(
    const float* __restrict__ ax, const float* __restrict__ nx,
    const float* __restrict__ a_wih, const float* __restrict__ a_whh,
    const float* __restrict__ a_bih, const float* __restrict__ a_bhh,
    const float* __restrict__ n_wih, const float* __restrict__ n_whh,
    const float* __restrict__ n_bih, const float* __restrict__ n_bhh,
    float* __restrict__ nh_out, float* __restrict__ ah_out)
{
    const int tid = threadIdx.x, blk = blockIdx.x;
    const bool agent = (blk >= 1024);
    const int seq0 = (agent ? (blk - 1024) : blk) * 16;
    const float* __restrict__ x   = agent ? ax : nx;
    const float* __restrict__ wih = agent ? a_wih : n_wih;
    const float* __restrict__ whh = agent ? a_whh : n_whh;
    const float* __restrict__ bih = agent ? a_bih : n_bih;
    const float* __restrict__ bhh = agent ? a_bhh : n_bhh;
    float* __restrict__ hout = agent ? ah_out : nh_out;

    const int lane = tid & 63, wv = tid >> 6;
    const int col = lane & 15, quad = lane >> 4;

    __shared__ __attribute__((aligned(16))) uint hb[2][16][HS];
    __shared__ __attribute__((aligned(16))) ushort_t xb[50][16][8];

    // A fragments: Whh rows, single RTN bf16, pre-scaled by log2e (2log2e for
    // the g gate). A row = g*64+16wv+col.
    bf16x8 Aw[4][2];
    #pragma unroll
    for (int g = 0; g < 4; ++g) {
        const float sc = (g == 2) ? LOG2E2 : LOG2E;
        #pragma unroll
        for (int kt = 0; kt < 2; ++kt) {
            const float* p = whh + (size_t)(g * 64 + 16 * wv + col) * 64 + kt * 32 + quad * 8;
            float4 v0 = *(const float4*)p;
            float4 v1 = *(const float4*)(p + 4);
            float vv[8] = { v0.x, v0.y, v0.z, v0.w, v1.x, v1.y, v1.z, v1.w };
            bf16x8 h8;
            #pragma unroll
            for (int j = 0; j < 8; ++j) h8[j] = (short)bf_rtn(vv[j] * sc);
            Aw[g][kt] = h8;
        }
    }

    // 3rd-tile A fragments (x + bias, pre-scaled): nonzero only on quad 0.
    bf16x8 Ax[4];
    #pragma unroll
    for (int g = 0; g < 4; ++g) {
        const float sc = (g == 2) ? LOG2E2 : LOG2E;
        bf16x8 a;
        #pragma unroll
        for (int j = 0; j < 8; ++j) a[j] = 0;
        if (quad == 0) {
            const int row = g * 64 + 16 * wv + col;
            float w0 = wih[2 * row] * sc, w1 = wih[2 * row + 1] * sc;
            float b  = (bih[row] + bhh[row]) * sc;
            ushort_t w0h = bf_hi(w0), w1h = bf_hi(w1);
            ushort_t bh  = bf_hi(b);
            a[0] = (short)w0h;
            a[1] = (short)w1h;
            a[2] = (short)bf_hi(w0 - bf_f(w0h));
            a[3] = (short)bf_hi(w1 - bf_f(w1h));
            a[4] = (short)w0h;
            a[5] = (short)w1h;
            a[6] = (short)bh;
            a[7] = (short)bf_hi(b - bf_f(bh));
        }
        Ax[g] = a;
    }

    for (int idx = tid; idx < 50 * 16; idx += 256) {
        const int t = idx >> 4, s = idx & 15;
        const float* xp = x + (size_t)(seq0 + s) * 100 + 2 * t;
        float x0 = xp[0], x1 = xp[1];
        ushort_t h0 = bf_hi(x0), h1 = bf_hi(x1);
        ushort_t* e = &xb[t][s][0];
        e[0] = h0; e[1] = h1;
        e[2] = h0; e[3] = h1;
        e[4] = bf_hi(x0 - bf_f(h0));
        e[5] = bf_hi(x1 - bf_f(h1));
        e[6] = 0x3F80; e[7] = 0x3F80;
    }
    for (int i = tid; i < 16 * HS; i += 256) (&hb[0][0][0])[i] = 0u;
    __syncthreads();

    float c[4] = {0.f, 0.f, 0.f, 0.f};
    float hv[4];
    bf16x8 Bx = *(const bf16x8*)&xb[0][col][0];   // prefetched x-tile, t=0

    for (int t = 0; t < 50; ++t) {
        const int cur = t & 1, nxt = cur ^ 1;

        const f32x4 z4 = {0.f, 0.f, 0.f, 0.f};
        f32x4 acc[4];
        #pragma unroll
        for (int g = 0; g < 4; ++g)
            acc[g] = __builtin_amdgcn_mfma_f32_16x16x32_bf16(Ax[g], Bx, z4, 0, 0, 0);

        // Whh @ h: 1 MFMA per gate per kt
        #pragma unroll
        for (int kt = 0; kt < 2; ++kt) {
            bf16x8 Bhi = *(const bf16x8*)&hb[cur][col][kt * 16 + quad * 4];
            #pragma unroll
            for (int g = 0; g < 4; ++g)
                acc[g] = __builtin_amdgcn_mfma_f32_16x16x32_bf16(Aw[g][kt], Bhi, acc[g], 0, 0, 0);
        }

        // cell update: lane owns seq=col, units 16wv + 4quad + r
        #pragma unroll
        for (int r = 0; r < 4; ++r)
            hv[r] = cell_update_p(acc[0][r], acc[1][r], acc[2][r], acc[3][r], c[r]);

        // pack h (packed RTN cvt) -> LDS
        {
            __hip_bfloat162 p01 = __float22bfloat162_rn(make_float2(hv[0], hv[1]));
            __hip_bfloat162 p23 = __float22bfloat162_rn(make_float2(hv[2], hv[3]));
            uint2 hi2;
            union { __hip_bfloat162 b; uint u; } c0, c1;
            c0.b = p01; c1.b = p23;
            hi2.x = c0.u;
            hi2.y = c1.u;
            const int di = 8 * wv + 2 * quad;
            *(uint2*)&hb[nxt][col][di] = hi2;
        }
        // prefetch next x-tile BEFORE the barrier (xb is read-only: safe)
        if (t < 49) Bx = *(const bf16x8*)&xb[t + 1][col][0];
        __syncthreads();
    }

    // peeled final store (hv holds t=49 values)
    {
        float4 o4 = make_float4(hv[0], hv[1], hv[2], hv[3]);
        *(float4*)(hout + (size_t)(seq0 + col) * 64 + 16 * wv + 4 * quad) = o4;
    }
}

// ============== decoder: R1-vintage fp32 (validated, ~25us) ================
__global__ __launch_bounds__(512) void dec14_kernel(
    const float* __restrict__ ah, const float* __restrict__ nh,
    const float* __restrict__ d_wih, const float* __restrict__ d_whh,
    const float* __restrict__ d_bih, const float* __restrict__ d_bhh,
    const float* __restrict__ e_w, const float* __restrict__ e_b,
    float* __restrict__ out)
{
    const int tid = threadIdx.x;
    const int blk = blockIdx.x;

    const int u  = tid >> 2;
    const int tt = tid & 3;
    const int r  = tt * 128 + u;

    float w[128];
    #pragma unroll
    for (int k = 0; k < 128; k += 4) {
        float4 aa = *(const float4*)(d_wih + r * 128 + k);
        float4 bb = *(const float4*)(d_whh + r * 128 + k);
        w[k]   = aa.x + bb.x;
        w[k+1] = aa.y + bb.y;
        w[k+2] = aa.z + bb.z;
        w[k+3] = aa.w + bb.w;
    }
    const float bias = d_bih[r] + d_bhh[r];

    __shared__ float hs[2][128];
    __shared__ float cs[2][128];
    __shared__ float gs[2][512];
    __shared__ float ews[2][128];
    __shared__ float ebs[2];

    if (tid < 256) {
        const int s = tid >> 7, j = tid & 127;
        const int gseq = blk * 2 + s;
        float v;
        if (j < 64) {
            v = ah[(size_t)gseq * 64 + j];
        } else {
            float acc = 0.0f;
            for (int n = 0; n < 32; ++n)
                acc += nh[(size_t)(gseq * 32 + n) * 64 + (j - 64)];
            v = acc * (1.0f / 32.0f);
        }
        hs[s][j] = v;
        cs[s][j] = 0.0f;
        ews[s][j] = e_w[tid];
    }
    if (tid < 2) ebs[tid] = e_b[tid];
    __syncthreads();

    for (int t = 0; t < 30; ++t) {
        #pragma unroll
        for (int s = 0; s < 2; ++s) {
            const float4* hp = (const float4*)(&hs[s][0]);
            float a0 = 0.f, a1 = 0.f, a2 = 0.f, a3 = 0.f;
            #pragma unroll
            for (int k = 0; k < 32; ++k) {
                float4 h4 = hp[k];
                a0 = __builtin_fmaf(w[4*k+0], h4.x, a0);
                a1 = __builtin_fmaf(w[4*k+1], h4.y, a1);
                a2 = __builtin_fmaf(w[4*k+2], h4.z, a2);
                a3 = __builtin_fmaf(w[4*k+3], h4.w, a3);
            }
            gs[s][tid] = bias + ((a0 + a1) + (a2 + a3));
        }
        __syncthreads();
        if (tid < 256) {
            const int s = tid >> 7, j = tid & 127;
            float4 g4 = *(const float4*)(&gs[s][4 * j]);
            float ig = sigf(g4.x), fg = sigf(g4.y);
            float gg = tanh_fast(g4.z), og = sigf(g4.w);
            float cc = fg * cs[s][j] + ig * gg;
            cs[s][j] = cc;
            hs[s][j] = og * tanh_fast(cc);
        }
        __syncthreads();
        {
            const int wv = tid >> 6, l = tid & 63;
            if (wv < 4) {
                const int s = wv >> 1, o = wv & 1;
                float p = hs[s][l] * ews[o][l] + hs[s][64 + l] * ews[o][64 + l];
                #pragma unroll
                for (int off = 32; off > 0; off >>= 1) p += __shfl_down(p, off);
                if (l == 0) out[((size_t)(blk * 2 + s) * 30 + t) * 2 + o] = p + ebs[o];
            }
        }
    }
}

extern "C" void kernel_launch(void* const* d_in, const int* in_sizes, int n_in,
                              void* d_out, int out_size, void* d_ws, size_t ws_size,
                              hipStream_t stream)
{
    const float* agent_traj = (const float*)d_in[0];
    const float* neigh_traj = (const float*)d_in[1];
    const float* a_wih = (const float*)d_in[2];
    const float* a_whh = (const float*)d_in[3];
    const float* a_bih = (const float*)d_in[4];
    const float* a_bhh = (const float*)d_in[5];
    const float* n_wih = (const float*)d_in[6];
    const float* n_whh = (const float*)d_in[7];
    const float* n_bih = (const float*)d_in[8];
    const float* n_bhh = (const float*)d_in[9];
    const float* d_wih = (const float*)d_in[10];
    const float* d_whh = (const float*)d_in[11];
    const float* d_bih = (const float*)d_in[12];
    const float* d_bhh = (const float*)d_in[13];
    const float* e_w   = (const float*)d_in[14];
    const float* e_b   = (const float*)d_in[15];
    float* out = (float*)d_out;

    float* nh_ws = (float*)d_ws;            // 16384*64 fp32
    float* ah_ws = nh_ws + 16384 * 64;      // 512*64 fp32

    enc14_kernel<<<dim3(1024 + 32), dim3(256), 0, stream>>>(
        agent_traj, neigh_traj,
        a_wih, a_whh, a_bih, a_bhh,
        n_wih, n_whh, n_bih, n_bhh,
        nh_ws, ah_ws);

    dec14_kernel<<<dim3(256), dim3(512), 0, stream>>>(
        ah_ws, nh_ws, d_wih, d_whh, d_bih, d_bhh, e_w, e_b, out);
}